// Round 5
// baseline (3328.389 us; speedup 1.0000x reference)
//
#include <hip/hip_runtime.h>
#include <hip/hip_bf16.h>

typedef __attribute__((ext_vector_type(8))) short bf16x8;
typedef __attribute__((ext_vector_type(4))) float f32x4;
typedef __attribute__((ext_vector_type(4))) unsigned u32x4;
typedef __attribute__((ext_vector_type(2))) unsigned u32x2;

#define SEQT 2048
#define BATCH 32
#define INDIM 512
#define EMB 256
#define HHX 128
#define LBL 16
#define LOG2E 1.44269504f

__device__ __forceinline__ unsigned short f2bf(float f) {
    unsigned u = __float_as_uint(f);
    u += 0x7FFFu + ((u >> 16) & 1u);
    return (unsigned short)(u >> 16);
}
#define BLO(u) __uint_as_float((u) << 16)
#define BHI(u) __uint_as_float((u) & 0xffff0000u)

// merged-rcp LSTM cell: 5 exp2 + 3 rcp, inf-safe per factor.
__device__ __forceinline__ float cell(float ig, float fg, float gg, float og, float& c) {
    float Ef = __builtin_amdgcn_exp2f(-LOG2E * fg);
    float Ei = __builtin_amdgcn_exp2f(-LOG2E * ig);
    float Eg = __builtin_amdgcn_exp2f(fminf(2.f * LOG2E * gg, 80.f));
    float Eo = __builtin_amdgcn_exp2f(-LOG2E * og);
    float r1 = __builtin_amdgcn_rcpf(1.f + Ef);
    float r2 = __builtin_amdgcn_rcpf((Eg + 1.f) * (1.f + Ei));
    float cn = c * r1 + (Eg - 1.f) * r2;
    c = cn;
    float E2 = __builtin_amdgcn_exp2f(fminf(2.f * LOG2E * cn, 80.f));
    float r3 = __builtin_amdgcn_rcpf((E2 + 1.f) * (1.f + Eo));
    return (E2 - 1.f) * r3;
}

// Gate-row permutation (transposed formulation):
// perm row R (0..511): tile=R>>4, r=R&15, unit=tile*4+(r>>2), gate=r&3 (i,f,g,o)
// orig row = gate*128 + unit
__device__ __forceinline__ int orig_of(int R) {
    int r = R & 15;
    return (r & 3) * 128 + (R >> 4) * 4 + (r >> 2);
}

// ---------------- prep: combined W (Wih @ in_W) + bias, permuted rows; 8 rows/block ----------------
__global__ __launch_bounds__(256) void k_prep_wc(
    const float* __restrict__ in_W, const float* __restrict__ in_b,
    const float* __restrict__ Wih_f, const float* __restrict__ b_f,
    const float* __restrict__ Wih_b, const float* __restrict__ b_b,
    unsigned short* __restrict__ Wc, float* __restrict__ bc)
{
    int G0 = blockIdx.x * 8;         // 128 blocks
    int tid = threadIdx.x;
    __shared__ float wrow[8][EMB];
    for (int e = tid; e < 8 * EMB; e += 256) {
        int r = e >> 8, ee = e & 255;
        int G = G0 + r, dir = G >> 9;
        wrow[r][ee] = (dir ? Wih_b : Wih_f)[orig_of(G & 511) * EMB + ee];
    }
    __syncthreads();
    for (int k = tid; k < INDIM; k += 256) {
        float acc[8] = {0, 0, 0, 0, 0, 0, 0, 0};
        #pragma unroll 4
        for (int e = 0; e < EMB; ++e) {
            float x = in_W[e * INDIM + k];
            #pragma unroll
            for (int r = 0; r < 8; ++r) acc[r] += wrow[r][e] * x;
        }
        #pragma unroll
        for (int r = 0; r < 8; ++r) Wc[(size_t)(G0 + r) * INDIM + k] = f2bf(acc[r]);
    }
    if (tid < 64) {
        for (int r = 0; r < 8; ++r) {
            float p = 0.f;
            for (int e = tid; e < EMB; e += 64) p += wrow[r][e] * in_b[e];
            for (int off = 32; off; off >>= 1) p += __shfl_xor(p, off);
            if (tid == 0) {
                int G = G0 + r, dir = G >> 9;
                bc[G] = (dir ? b_b : b_f)[orig_of(G & 511)] + p;
            }
        }
    }
}

// ---------------- prep: bf16 converts (Whh permuted, out_W) ----------------
__global__ __launch_bounds__(256) void k_prep_misc(
    const float* __restrict__ Whh_f, const float* __restrict__ Whh_b,
    const float* __restrict__ out_W,
    unsigned short* __restrict__ Whh_bf, unsigned short* __restrict__ outW_bf)
{
    int idx = blockIdx.x * 256 + threadIdx.x;
    int stride = gridDim.x * 256;
    for (int i = idx; i < 1024 * HHX; i += stride) {
        int G = i >> 7, k = i & 127;
        int dir = G >> 9;
        const float* Whh = dir ? Whh_b : Whh_f;
        Whh_bf[i] = f2bf(Whh[orig_of(G & 511) * HHX + k]);
    }
    for (int i = idx; i < LBL * 256; i += stride) outW_bf[i] = f2bf(out_W[i]);
}

// ---------------- big GEMM (flipped): C[1024 gates][65536 m] = Wc @ S^T + bc ----------------
// P2[(t*4 + dir*2 + bt)][1024 threads][8]: lstm thread's 8 gate pre-acts contiguous (16B).
__global__ __launch_bounds__(512) void k_gemm_p(
    const float* __restrict__ S, const unsigned short* __restrict__ Wc,
    const float* __restrict__ bc, unsigned short* __restrict__ P2)
{
    int m0g = blockIdx.y * 256;      // gate rows
    int n0 = blockIdx.x * 64;        // m = t*32 + b
    int tid = threadIdx.x;
    int w = tid >> 6, l = tid & 63;
    int lr = l & 15, lq = l >> 4;
    int wm = w >> 1, wn = w & 1;     // 4 m-wave-tiles x 2 n-wave-tiles

    __shared__ __align__(16) unsigned short Alds[256 * 64];  // gates x k
    __shared__ __align__(16) unsigned short Blds[64 * 64];   // m x k

    const f32x4 fzero = {0.f, 0.f, 0.f, 0.f};
    f32x4 acc[4][2];
    #pragma unroll
    for (int a = 0; a < 4; ++a)
        #pragma unroll
        for (int b = 0; b < 2; ++b) acc[a][b] = fzero;

    for (int kt = 0; kt < 8; ++kt) {
        { // stage A: Wc rows (bf16), XOR-swizzled 128B rows
            int r = tid >> 1, h2 = tid & 1;
            const unsigned short* as = Wc + (size_t)(m0g + r) * INDIM + kt * 64;
            #pragma unroll
            for (int cc = 0; cc < 4; ++cc) {
                int ch = h2 * 4 + cc;
                bf16x8 v = *(const bf16x8*)(as + ch * 8);
                *(bf16x8*)((char*)Alds + r * 128 + ((ch * 16) ^ ((r & 7) << 4))) = v;
            }
        }
        { // stage B: S rows (fp32 -> bf16 via cvt_pk)
            int r = tid >> 3, c = tid & 7;
            const float* src = S + (size_t)(n0 + r) * INDIM + kt * 64 + c * 8;
            float4 v0 = *(const float4*)src;
            float4 v1 = *(const float4*)(src + 4);
            unsigned g0, g1, g2, g3;
            asm("v_cvt_pk_bf16_f32 %0, %1, %2" : "=v"(g0) : "v"(v0.x), "v"(v0.y));
            asm("v_cvt_pk_bf16_f32 %0, %1, %2" : "=v"(g1) : "v"(v0.z), "v"(v0.w));
            asm("v_cvt_pk_bf16_f32 %0, %1, %2" : "=v"(g2) : "v"(v1.x), "v"(v1.y));
            asm("v_cvt_pk_bf16_f32 %0, %1, %2" : "=v"(g3) : "v"(v1.z), "v"(v1.w));
            u32x4 wv = {g0, g1, g2, g3};
            *(u32x4*)((char*)Blds + r * 128 + ((c * 16) ^ ((r & 7) << 4))) = wv;
        }
        __syncthreads();
        bf16x8 afr[4][2], bfr[2][2];
        #pragma unroll
        for (int tg = 0; tg < 4; ++tg)
            #pragma unroll
            for (int kk = 0; kk < 2; ++kk) {
                int ra = wm * 64 + tg * 16 + lr;
                afr[tg][kk] = *(const bf16x8*)((char*)Alds + ra * 128 + ((kk * 64 + lq * 16) ^ ((ra & 7) << 4)));
            }
        #pragma unroll
        for (int tb = 0; tb < 2; ++tb)
            #pragma unroll
            for (int kk = 0; kk < 2; ++kk) {
                int rb = wn * 32 + tb * 16 + lr;
                bfr[tb][kk] = *(const bf16x8*)((char*)Blds + rb * 128 + ((kk * 64 + lq * 16) ^ ((rb & 7) << 4)));
            }
        #pragma unroll
        for (int tg = 0; tg < 4; ++tg)
            #pragma unroll
            for (int tb = 0; tb < 2; ++tb)
                #pragma unroll
                for (int kk = 0; kk < 2; ++kk)
                    acc[tg][tb] = __builtin_amdgcn_mfma_f32_16x16x32_bf16(afr[tg][kk], bfr[tb][kk], acc[tg][tb], 0, 0, 0);
        __syncthreads();
    }
    // epilogue: lane's 4 j-values = gates i,f,g,o of one unit -> one u32x2 store
    #pragma unroll
    for (int tg = 0; tg < 4; ++tg) {
        int R = m0g + wm * 64 + tg * 16 + lq * 4;        // +j
        float4 b4 = *(const float4*)(bc + R);
        int dir = R >> 9, R9 = R & 511, tile = R9 >> 4;
        int slot = (tile & 1) * 4;
        int thr_hi = (tile >> 1) * 64 + lq * 16;
        #pragma unroll
        for (int tb = 0; tb < 2; ++tb) {
            int mcol = n0 + wn * 32 + tb * 16 + lr;
            int t = mcol >> 5, bt = (mcol >> 4) & 1, lrb = mcol & 15;
            size_t idx = (((size_t)(t * 4 + dir * 2 + bt)) * 1024 + thr_hi + lrb) * 8 + slot;
            float f0 = acc[tg][tb][0] + b4.x, f1 = acc[tg][tb][1] + b4.y;
            float f2 = acc[tg][tb][2] + b4.z, f3 = acc[tg][tb][3] + b4.w;
            unsigned p01, p23;
            asm("v_cvt_pk_bf16_f32 %0, %1, %2" : "=v"(p01) : "v"(f0), "v"(f1));
            asm("v_cvt_pk_bf16_f32 %0, %1, %2" : "=v"(p23) : "v"(f2), "v"(f3));
            *(u32x2*)(P2 + idx) = (u32x2){p01, p23};
        }
    }
}

// ---------------- LSTM recurrence: 4 blocks x 1024 threads (16 waves), transposed MFMA ----------------
__global__ __launch_bounds__(1024) void k_lstm(
    const unsigned short* __restrict__ P2, const unsigned short* __restrict__ Whh_bf,
    const float* __restrict__ h0, const float* __restrict__ c0,
    unsigned short* __restrict__ H)
{
    int blk = blockIdx.x;
    int dir = blk >> 1, bt = blk & 1;
    int tid = threadIdx.x;
    int w = tid >> 6, l = tid & 63;   // w: 0..15
    int lr = l & 15, lq = l >> 4;

    __shared__ __align__(16) unsigned short hbuf[2][16 * 128];  // [batch16][unit128]
    char* hb = (char*)hbuf;

    // A-frags: wave w owns tiles 2w, 2w+1 -> units 8w+lq, 8w+4+lq
    bf16x8 afr[2][4];
    #pragma unroll
    for (int tp = 0; tp < 2; ++tp)
        #pragma unroll
        for (int kk = 0; kk < 4; ++kk) {
            int row = dir * 512 + (2 * w + tp) * 16 + lr;
            afr[tp][kk] = *(const bf16x8*)(Whh_bf + (size_t)row * HHX + kk * 32 + lq * 8);
        }

    int unit0 = 8 * w + lq;
    float c_reg[2];
    c_reg[0] = c0[(dir * 32 + bt * 16 + lr) * HHX + unit0];
    c_reg[1] = c0[(dir * 32 + bt * 16 + lr) * HHX + unit0 + 4];

    for (int e = tid; e < 2048; e += 1024) {
        int b = e >> 7, u = e & 127;
        float hv = h0[(dir * 32 + bt * 16 + b) * HHX + u];
        *(unsigned short*)(hb + ((b * 256 + u * 2) ^ ((b & 7) << 4))) = f2bf(hv);
    }
    __syncthreads();

    // loop-invariant LDS offsets (rows = batch lr)
    const int sw = (lr & 7) << 4;
    const int rd0 = (lr * 256 + 0 * 64 + lq * 16) ^ sw;
    const int rd1 = (lr * 256 + 1 * 64 + lq * 16) ^ sw;
    const int rd2 = (lr * 256 + 2 * 64 + lq * 16) ^ sw;
    const int rd3 = (lr * 256 + 3 * 64 + lq * 16) ^ sw;
    const int wa = (lr * 256 + unit0 * 2) ^ sw;   // +8 bytes for unit0+4 (XOR bits untouched)

    int t0 = dir ? (SEQT - 1) : 0;
    const long long pstep = (dir ? -1LL : 1LL) * (4LL * 1024 * 8);
    const unsigned short* pptr = P2 + ((size_t)(t0 * 4 + dir * 2 + bt)) * 1024 * 8 + (size_t)tid * 8;
    bf16x8 pc = *(const bf16x8*)pptr;
    pptr += pstep;

    unsigned short* hptr = H + (size_t)(t0 * 32 + bt * 16 + lr) * 256 + dir * 128 + unit0;
    const long long hstep = (dir ? -1LL : 1LL) * (32 * 256);

#define STEP(CUR, PF) do { \
    bf16x8 bf0 = *(const bf16x8*)(hb + (CUR) * 4096 + rd0); \
    bf16x8 bf1 = *(const bf16x8*)(hb + (CUR) * 4096 + rd1); \
    bf16x8 bf2 = *(const bf16x8*)(hb + (CUR) * 4096 + rd2); \
    bf16x8 bf3 = *(const bf16x8*)(hb + (CUR) * 4096 + rd3); \
    u32x4 up = __builtin_bit_cast(u32x4, pc); \
    if (PF) { pc = *(const bf16x8*)pptr; pptr += pstep; } \
    f32x4 a0 = {BLO(up.x), BHI(up.x), BLO(up.y), BHI(up.y)}; \
    f32x4 a1 = {BLO(up.z), BHI(up.z), BLO(up.w), BHI(up.w)}; \
    a0 = __builtin_amdgcn_mfma_f32_16x16x32_bf16(afr[0][0], bf0, a0, 0, 0, 0); \
    a0 = __builtin_amdgcn_mfma_f32_16x16x32_bf16(afr[0][1], bf1, a0, 0, 0, 0); \
    a0 = __builtin_amdgcn_mfma_f32_16x16x32_bf16(afr[0][2], bf2, a0, 0, 0, 0); \
    a0 = __builtin_amdgcn_mfma_f32_16x16x32_bf16(afr[0][3], bf3, a0, 0, 0, 0); \
    a1 = __builtin_amdgcn_mfma_f32_16x16x32_bf16(afr[1][0], bf0, a1, 0, 0, 0); \
    a1 = __builtin_amdgcn_mfma_f32_16x16x32_bf16(afr[1][1], bf1, a1, 0, 0, 0); \
    a1 = __builtin_amdgcn_mfma_f32_16x16x32_bf16(afr[1][2], bf2, a1, 0, 0, 0); \
    a1 = __builtin_amdgcn_mfma_f32_16x16x32_bf16(afr[1][3], bf3, a1, 0, 0, 0); \
    float h0v = cell(a0[0], a0[1], a0[2], a0[3], c_reg[0]); \
    float h1v = cell(a1[0], a1[1], a1[2], a1[3], c_reg[1]); \
    unsigned pk; \
    asm("v_cvt_pk_bf16_f32 %0, %1, %2" : "=v"(pk) : "v"(h0v), "v"(h1v)); \
    char* wbp = hb + (((CUR) ^ 1) * 4096); \
    *(unsigned short*)(wbp + wa) = (unsigned short)pk; \
    *(unsigned short*)(wbp + wa + 8) = (unsigned short)(pk >> 16); \
    hptr[0] = (unsigned short)pk; \
    hptr[4] = (unsigned short)(pk >> 16); \
    hptr += hstep; \
    __syncthreads(); \
} while (0)

    for (int it = 0; it < 1023; ++it) {
        STEP(0, true);
        STEP(1, true);
    }
    STEP(0, true);
    STEP(1, false);
#undef STEP
}

// ---------------- feats: F(65536x16) = H @ outW^T + out_b ----------------
__global__ __launch_bounds__(256) void k_feats(
    const unsigned short* __restrict__ H, const unsigned short* __restrict__ outW_bf,
    const float* __restrict__ out_b, float* __restrict__ feats)
{
    int m0 = blockIdx.x * 64;
    int tid = threadIdx.x;
    int w = tid >> 6, l = tid & 63;
    int lr = l & 15, lq = l >> 4;
    __shared__ __align__(16) unsigned short Hl[64 * 256];

    {
        int r = tid >> 2, cb = (tid & 3) * 8;
        #pragma unroll
        for (int cc = 0; cc < 8; ++cc) {
            int c = cb + cc;
            bf16x8 v = *(const bf16x8*)(H + (size_t)(m0 + r) * 256 + c * 8);
            *(bf16x8*)((char*)Hl + r * 512 + ((c * 16) ^ ((r & 7) << 4))) = v;
        }
    }
    bf16x8 bw[8];
    #pragma unroll
    for (int ko = 0; ko < 8; ++ko)
        bw[ko] = *(const bf16x8*)(outW_bf + lr * 256 + ko * 32 + lq * 8);
    __syncthreads();
    int row = w * 16 + lr;
    f32x4 acc = {0.f, 0.f, 0.f, 0.f};
    #pragma unroll
    for (int ko = 0; ko < 8; ++ko) {
        bf16x8 a = *(const bf16x8*)((char*)Hl + row * 512 + ((ko * 64 + lq * 16) ^ ((row & 7) << 4)));
        acc = __builtin_amdgcn_mfma_f32_16x16x32_bf16(a, bw[ko], acc, 0, 0, 0);
    }
    float ob = out_b[lr];
    #pragma unroll
    for (int j = 0; j < 4; ++j) {
        int m = m0 + w * 16 + lq * 4 + j;
        feats[(size_t)m * 16 + lr] = acc[j] + ob;
    }
}

// ---------------- Viterbi: 1 block per batch, 1 wave; DPP reduce + packed backtrack ----------------
template <int CTRL>
__device__ __forceinline__ float dppf(float x) {
    return __int_as_float(__builtin_amdgcn_update_dpp(0, __float_as_int(x), CTRL, 0xF, 0xF, true));
}
template <int CTRL>
__device__ __forceinline__ int dppi(int x) {
    return __builtin_amdgcn_update_dpp(0, x, CTRL, 0xF, 0xF, true);
}

__global__ __launch_bounds__(64) void k_viterbi(
    const float* __restrict__ feats, const float* __restrict__ trans,
    float* __restrict__ out)
{
    int b = blockIdx.x;
    int l = threadIdx.x;
    int i = l >> 2, s = l & 3;          // i = next-label (0..15), s = prev-quad (0..3)
    __shared__ unsigned char bp[SEQT * 16];
    __shared__ __align__(16) float fch[256 * 16];
    __shared__ unsigned long long bp64[SEQT];

    float tr[4];
    #pragma unroll
    for (int m = 0; m < 4; ++m) tr[m] = trans[i * 16 + s * 4 + m];
    float fvloc[4];
    #pragma unroll
    for (int m = 0; m < 4; ++m) fvloc[m] = (s * 4 + m == 0) ? 0.f : -10000.f;

    int ga[4];
    #pragma unroll
    for (int m = 0; m < 4; ++m) ga[m] = (16 * s + 4 * m) * 4;   // bpermute byte addr

    for (int t = 0; t < SEQT; ++t) {
        if ((t & 255) == 0) {
            __syncthreads();
            for (int k = l; k < 256; k += 64) {
                const float4* src = (const float4*)(feats + (size_t)((t + k) * 32 + b) * 16);
                float4 v0 = src[0], v1 = src[1], v2 = src[2], v3 = src[3];
                float4* dst = (float4*)(fch + k * 16);
                dst[0] = v0; dst[1] = v1; dst[2] = v2; dst[3] = v3;
            }
            __syncthreads();
        }
        float best = fvloc[0] + tr[0];
        int bj = s * 4;
        #pragma unroll
        for (int m = 1; m < 4; ++m) {
            float v = fvloc[m] + tr[m];
            if (v > best) { best = v; bj = s * 4 + m; }
        }
        { // quad xor1 via DPP quad_perm [1,0,3,2]
            float ov = dppf<0xB1>(best); int oj = dppi<0xB1>(bj);
            bool take = (ov > best) || (ov == best && oj < bj);
            best = take ? ov : best; bj = take ? oj : bj;
        }
        { // quad xor2 via DPP quad_perm [2,3,0,1]
            float ov = dppf<0x4E>(best); int oj = dppi<0x4E>(bj);
            bool take = (ov > best) || (ov == best && oj < bj);
            best = take ? ov : best; bj = take ? oj : bj;
        }
        float fvn = best + fch[(t & 255) * 16 + i];
        if (s == 0) bp[t * 16 + i] = (unsigned char)bj;
        #pragma unroll
        for (int m = 0; m < 4; ++m)
            fvloc[m] = __int_as_float(__builtin_amdgcn_ds_bpermute(ga[m], __float_as_int(fvn)));
    }
    // termination
    float bestS = fvloc[0] + trans[16 + s * 4];
    int bl = s * 4;
    #pragma unroll
    for (int m = 1; m < 4; ++m) {
        float tv = fvloc[m] + trans[16 + s * 4 + m];
        if (tv > bestS) { bestS = tv; bl = s * 4 + m; }
    }
    {
        float ov = dppf<0xB1>(bestS); int oj = dppi<0xB1>(bl);
        bool take = (ov > bestS) || (ov == bestS && oj < bl);
        bestS = take ? ov : bestS; bl = take ? oj : bl;
    }
    {
        float ov = dppf<0x4E>(bestS); int oj = dppi<0x4E>(bl);
        bool take = (ov > bestS) || (ov == bestS && oj < bl);
        bestS = take ? ov : bestS; bl = take ? oj : bl;
    }
    __syncthreads();
    // pack bp rows into nibble-u64 (address-independent backtrack reads)
    for (int t = l; t < SEQT; t += 64) {
        const uint4* p = (const uint4*)(bp + t * 16);
        uint4 u = *p;
        unsigned n0 = (u.x | (u.x >> 4)) & 0x00FF00FFu; n0 = (n0 | (n0 >> 8)) & 0xFFFFu;
        unsigned n1 = (u.y | (u.y >> 4)) & 0x00FF00FFu; n1 = (n1 | (n1 >> 8)) & 0xFFFFu;
        unsigned n2 = (u.z | (u.z >> 4)) & 0x00FF00FFu; n2 = (n2 | (n2 >> 8)) & 0xFFFFu;
        unsigned n3 = (u.w | (u.w >> 4)) & 0x00FF00FFu; n3 = (n3 | (n3 >> 8)) & 0xFFFFu;
        bp64[t] = (unsigned long long)n0 | ((unsigned long long)n1 << 16)
                | ((unsigned long long)n2 << 32) | ((unsigned long long)n3 << 48);
    }
    __syncthreads();
    if (l == 0) out[b] = bestS;
    // all lanes run the chain redundantly; lane t&63 stores t
    int lbl = bl;
    #pragma unroll 8
    for (int t = SEQT - 1; t >= 0; --t) {
        if ((t & 63) == l) out[32 + (size_t)t * 32 + b] = (float)lbl;
        lbl = (int)((bp64[t] >> (lbl * 4)) & 15ull);
    }
}

extern "C" void kernel_launch(void* const* d_in, const int* in_sizes, int n_in,
                              void* d_out, int out_size, void* d_ws, size_t ws_size,
                              hipStream_t stream) {
    const float* source = (const float*)d_in[0];
    const float* in_W  = (const float*)d_in[1];
    const float* in_b  = (const float*)d_in[2];
    const float* Wih_f = (const float*)d_in[3];
    const float* Whh_f = (const float*)d_in[4];
    const float* b_f   = (const float*)d_in[5];
    const float* Wih_b = (const float*)d_in[6];
    const float* Whh_b = (const float*)d_in[7];
    const float* b_b   = (const float*)d_in[8];
    const float* out_W = (const float*)d_in[9];
    const float* out_b = (const float*)d_in[10];
    const float* trans = (const float*)d_in[11];
    const float* h0    = (const float*)d_in[12];
    const float* c0    = (const float*)d_in[13];
    float* out = (float*)d_out;

    char* ws = (char*)d_ws;
    unsigned short* P2      = (unsigned short*)(ws);                 // 2048*4*1024*8*2 = 134217728
    unsigned short* H       = (unsigned short*)(ws + 134217728);     // 65536*256*2  =  33554432
    float*          feats   = (float*)         (ws + 167772160);     // 65536*16*4   =   4194304
    unsigned short* Wc      = (unsigned short*)(ws + 171966464);     // 1024*512*2   =   1048576
    float*          bc      = (float*)         (ws + 173015040);     // 1024*4
    unsigned short* Whh_bf  = (unsigned short*)(ws + 173019136);     // 1024*128*2   =    262144
    unsigned short* outW_bf = (unsigned short*)(ws + 173281280);     // 16*256*2
    // total ~173.3 MB

    hipLaunchKernelGGL(k_prep_wc, dim3(128), dim3(256), 0, stream,
                       in_W, in_b, Wih_f, b_f, Wih_b, b_b, Wc, bc);
    hipLaunchKernelGGL(k_prep_misc, dim3(256), dim3(256), 0, stream,
                       Whh_f, Whh_b, out_W, Whh_bf, outW_bf);
    hipLaunchKernelGGL(k_gemm_p, dim3(1024, 4), dim3(512), 0, stream,
                       source, Wc, bc, P2);
    hipLaunchKernelGGL(k_lstm, dim3(4), dim3(1024), 0, stream,
                       P2, Whh_bf, h0, c0, H);
    hipLaunchKernelGGL(k_feats, dim3(1024), dim3(256), 0, stream,
                       H, outW_bf, out_b, feats);
    hipLaunchKernelGGL(k_viterbi, dim3(32), dim3(64), 0, stream,
                       feats, trans, out);
}

// Round 6
// 2337.521 us; speedup vs baseline: 1.4239x; 1.4239x over previous
//
#include <hip/hip_runtime.h>
#include <hip/hip_bf16.h>

typedef __attribute__((ext_vector_type(8))) short bf16x8;
typedef __attribute__((ext_vector_type(4))) float f32x4;
typedef __attribute__((ext_vector_type(4))) unsigned u32x4;
typedef __attribute__((ext_vector_type(2))) unsigned u32x2;

#define SEQT 2048
#define BATCH 32
#define INDIM 512
#define EMB 256
#define HHX 128
#define LBL 16
#define LOG2E 1.44269504f

__device__ __forceinline__ unsigned short f2bf(float f) {
    unsigned u = __float_as_uint(f);
    u += 0x7FFFu + ((u >> 16) & 1u);
    return (unsigned short)(u >> 16);
}
#define BLO(u) __uint_as_float((u) << 16)
#define BHI(u) __uint_as_float((u) & 0xffff0000u)

// Pre-scaled cell: inputs already have -LOG2E (i,f,o) / +2*LOG2E (g) folded into
// the weights+bias, so gate pre-acts feed exp2 directly. 4 exp2 + 3 rcp + 1 exp2.
// Inf-safe: positive-arg exp2s clamped at 80; other saturation paths give exact limits.
__device__ __forceinline__ float cell(float ig, float fg, float gg, float og, float& c) {
    float Ef = __builtin_amdgcn_exp2f(fg);              // = 2^(-log2e*f)
    float Ei = __builtin_amdgcn_exp2f(ig);
    float Eg = __builtin_amdgcn_exp2f(fminf(gg, 80.f)); // = 2^(2*log2e*g)
    float Eo = __builtin_amdgcn_exp2f(og);
    float r1 = __builtin_amdgcn_rcpf(1.f + Ef);
    float r2 = __builtin_amdgcn_rcpf((Eg + 1.f) * (1.f + Ei));
    float cn = c * r1 + (Eg - 1.f) * r2;
    c = cn;
    float E2 = __builtin_amdgcn_exp2f(fminf(2.f * LOG2E * cn, 80.f));
    float r3 = __builtin_amdgcn_rcpf((E2 + 1.f) * (1.f + Eo));
    return (E2 - 1.f) * r3;
}

// Gate-row permutation: g' = w*64 + q*16 + r  <->  orig = q*128 + w*16 + r
// q = gate (0=i,1=f,2=g,3=o)
__device__ __forceinline__ int orig_of(int gp) {
    return ((gp >> 4) & 3) * 128 + (gp >> 6) * 16 + (gp & 15);
}
__device__ __forceinline__ float gate_scale(int gp) {
    return (((gp >> 4) & 3) == 2) ? (2.f * LOG2E) : (-LOG2E);
}

// ---------------- prep: combined W (Wih @ in_W) + bias, permuted+scaled rows ----------------
__global__ __launch_bounds__(256) void k_prep_wc(
    const float* __restrict__ in_W, const float* __restrict__ in_b,
    const float* __restrict__ Wih_f, const float* __restrict__ b_f,
    const float* __restrict__ Wih_b, const float* __restrict__ b_b,
    unsigned short* __restrict__ Wc, float* __restrict__ bc)
{
    int G0 = blockIdx.x * 8;         // 128 blocks
    int tid = threadIdx.x;
    __shared__ float wrow[8][EMB];
    for (int e = tid; e < 8 * EMB; e += 256) {
        int r = e >> 8, ee = e & 255;
        int G = G0 + r, dir = G >> 9, gp = G & 511;
        wrow[r][ee] = (dir ? Wih_b : Wih_f)[orig_of(gp) * EMB + ee] * gate_scale(gp);
    }
    __syncthreads();
    for (int k = tid; k < INDIM; k += 256) {
        float acc[8] = {0, 0, 0, 0, 0, 0, 0, 0};
        #pragma unroll 4
        for (int e = 0; e < EMB; ++e) {
            float x = in_W[e * INDIM + k];
            #pragma unroll
            for (int r = 0; r < 8; ++r) acc[r] += wrow[r][e] * x;
        }
        #pragma unroll
        for (int r = 0; r < 8; ++r) Wc[(size_t)(G0 + r) * INDIM + k] = f2bf(acc[r]);
    }
    if (tid < 64) {
        for (int r = 0; r < 8; ++r) {
            float p = 0.f;
            for (int e = tid; e < EMB; e += 64) p += wrow[r][e] * in_b[e];
            for (int off = 32; off; off >>= 1) p += __shfl_xor(p, off);
            if (tid == 0) {
                int G = G0 + r, dir = G >> 9, gp = G & 511;
                bc[G] = (dir ? b_b : b_f)[orig_of(gp)] * gate_scale(gp) + p;
            }
        }
    }
}

// ---------------- prep: bf16 converts (Whh permuted+scaled, out_W) ----------------
__global__ __launch_bounds__(256) void k_prep_misc(
    const float* __restrict__ Whh_f, const float* __restrict__ Whh_b,
    const float* __restrict__ out_W,
    unsigned short* __restrict__ Whh_bf, unsigned short* __restrict__ outW_bf)
{
    int idx = blockIdx.x * 256 + threadIdx.x;
    int stride = gridDim.x * 256;
    for (int i = idx; i < 1024 * HHX; i += stride) {
        int G = i >> 7, k = i & 127;
        int dir = G >> 9, gp = G & 511;
        const float* Whh = dir ? Whh_b : Whh_f;
        Whh_bf[i] = f2bf(Whh[orig_of(gp) * HHX + k] * gate_scale(gp));
    }
    for (int i = idx; i < LBL * 256; i += stride) outW_bf[i] = f2bf(out_W[i]);
}

// ---------------- big GEMM: P2 = S @ Wc^T + bc, written in LSTM-thread layout ----------------
// P2[t][dir][bt][tid(512)][16]: each LSTM thread's 16 gate pre-acts contiguous (32B).
__global__ __launch_bounds__(512) void k_gemm_p(
    const float* __restrict__ S, const unsigned short* __restrict__ Wc,
    const float* __restrict__ bc, unsigned short* __restrict__ P2)
{
    int m0 = blockIdx.y * 64;
    int n0 = blockIdx.x * 256;
    int tid = threadIdx.x;
    int w = tid >> 6, l = tid & 63;
    int lr = l & 15, lq = l >> 4;
    int wm = w >> 2, wn = w & 3;

    __shared__ __align__(16) unsigned short Alds[64 * 64];
    __shared__ __align__(16) unsigned short Blds[256 * 64];

    const f32x4 fzero = {0.f, 0.f, 0.f, 0.f};
    f32x4 acc[2][4];
    #pragma unroll
    for (int a = 0; a < 2; ++a)
        #pragma unroll
        for (int b = 0; b < 4; ++b) acc[a][b] = fzero;

    for (int kt = 0; kt < 8; ++kt) {
        { // stage A (convert fp32->bf16 via cvt_pk, XOR-swizzled rows of 128B)
            int r = tid >> 3, c = tid & 7;
            const float* src = S + (size_t)(m0 + r) * INDIM + kt * 64 + c * 8;
            float4 v0 = *(const float4*)src;
            float4 v1 = *(const float4*)(src + 4);
            unsigned g0, g1, g2, g3;
            asm("v_cvt_pk_bf16_f32 %0, %1, %2" : "=v"(g0) : "v"(v0.x), "v"(v0.y));
            asm("v_cvt_pk_bf16_f32 %0, %1, %2" : "=v"(g1) : "v"(v0.z), "v"(v0.w));
            asm("v_cvt_pk_bf16_f32 %0, %1, %2" : "=v"(g2) : "v"(v1.x), "v"(v1.y));
            asm("v_cvt_pk_bf16_f32 %0, %1, %2" : "=v"(g3) : "v"(v1.z), "v"(v1.w));
            u32x4 wv = {g0, g1, g2, g3};
            *(u32x4*)((char*)Alds + r * 128 + ((c * 16) ^ ((r & 7) << 4))) = wv;
        }
        { // stage B
            int r = tid >> 1, h = tid & 1;
            const unsigned short* bs = Wc + (size_t)(n0 + r) * INDIM + kt * 64;
            #pragma unroll
            for (int cc = 0; cc < 4; ++cc) {
                int ch = h * 4 + cc;
                bf16x8 v = *(const bf16x8*)(bs + ch * 8);
                *(bf16x8*)((char*)Blds + r * 128 + ((ch * 16) ^ ((r & 7) << 4))) = v;
            }
        }
        __syncthreads();
        bf16x8 af[2][2], bfv[4][2];
        #pragma unroll
        for (int tm = 0; tm < 2; ++tm)
            #pragma unroll
            for (int kk = 0; kk < 2; ++kk) {
                int ra = wm * 32 + tm * 16 + lr;
                af[tm][kk] = *(const bf16x8*)((char*)Alds + ra * 128 + ((kk * 64 + lq * 16) ^ ((ra & 7) << 4)));
            }
        #pragma unroll
        for (int tn = 0; tn < 4; ++tn)
            #pragma unroll
            for (int kk = 0; kk < 2; ++kk) {
                int rb = wn * 64 + tn * 16 + lr;
                bfv[tn][kk] = *(const bf16x8*)((char*)Blds + rb * 128 + ((kk * 64 + lq * 16) ^ ((rb & 7) << 4)));
            }
        #pragma unroll
        for (int tm = 0; tm < 2; ++tm)
            #pragma unroll
            for (int tn = 0; tn < 4; ++tn)
                #pragma unroll
                for (int kk = 0; kk < 2; ++kk)
                    acc[tm][tn] = __builtin_amdgcn_mfma_f32_16x16x32_bf16(af[tm][kk], bfv[tn][kk], acc[tm][tn], 0, 0, 0);
        __syncthreads();
    }
    // epilogue: packed dwordx2 stores into LSTM-thread layout
    #pragma unroll
    for (int tn = 0; tn < 4; ++tn) {
        int n = n0 + wn * 64 + tn * 16 + lr;
        float bias = bc[n];
        int dir2 = n >> 9, nn = n & 511;
        int w2 = nn >> 6, q2 = (nn >> 4) & 3, lr2 = nn & 15;
        #pragma unroll
        for (int tm = 0; tm < 2; ++tm) {
            #pragma unroll
            for (int jj = 0; jj < 2; ++jj) {
                int m0j = m0 + wm * 32 + tm * 16 + lq * 4;
                int t = m0j >> 5, mb = m0j & 31;
                int bt2 = mb >> 4, lq2 = (mb >> 2) & 3;
                size_t base = ((size_t)(t * 4 + dir2 * 2 + bt2) * 512 + (w2 * 64 + lq2 * 16 + lr2)) * 16 + q2 * 4;
                if (jj == 0) {
                    float f0 = acc[tm][tn][0] + bias, f1 = acc[tm][tn][1] + bias;
                    float f2 = acc[tm][tn][2] + bias, f3 = acc[tm][tn][3] + bias;
                    unsigned p01, p23;
                    asm("v_cvt_pk_bf16_f32 %0, %1, %2" : "=v"(p01) : "v"(f0), "v"(f1));
                    asm("v_cvt_pk_bf16_f32 %0, %1, %2" : "=v"(p23) : "v"(f2), "v"(f3));
                    *(u32x2*)(P2 + base) = (u32x2){p01, p23};
                }
            }
        }
    }
}

// ---------------- LSTM recurrence: 4 blocks (dir x batch-tile), 512 threads ----------------
__global__ __launch_bounds__(512) void k_lstm(
    const unsigned short* __restrict__ P2, const unsigned short* __restrict__ Whh_bf,
    const float* __restrict__ h0, const float* __restrict__ c0,
    unsigned short* __restrict__ H)
{
    int blk = blockIdx.x;
    int dir = blk >> 1, bt = blk & 1;
    int tid = threadIdx.x;
    int w = tid >> 6, l = tid & 63;
    int lr = l & 15, lq = l >> 4;

    __shared__ __align__(16) unsigned short hbuf[2][16 * 128];
    char* hb = (char*)hbuf;

    // Whh fragments: wave w owns gates q=0..3 of units [w*16, w*16+16)
    bf16x8 bfrag[4][4];
    #pragma unroll
    for (int q = 0; q < 4; ++q)
        #pragma unroll
        for (int ko = 0; ko < 4; ++ko) {
            int row = dir * 512 + w * 64 + q * 16 + lr;
            bfrag[q][ko] = *(const bf16x8*)(Whh_bf + (size_t)row * HHX + ko * 32 + lq * 8);
        }

    float c_reg[4];
    #pragma unroll
    for (int j = 0; j < 4; ++j)
        c_reg[j] = c0[(dir * 32 + bt * 16 + lq * 4 + j) * HHX + w * 16 + lr];

    for (int e = tid; e < 2048; e += 512) {
        int b = e >> 7, u = e & 127;
        float hv = h0[(dir * 32 + bt * 16 + b) * HHX + u];
        *(unsigned short*)(hb + ((b * 256 + u * 2) ^ ((b & 7) << 4))) = f2bf(hv);
    }
    __syncthreads();

    // loop-invariant LDS offsets
    const int rd0 = (lr * 256 + 0 * 64 + lq * 16) ^ ((lr & 7) << 4);
    const int rd1 = (lr * 256 + 1 * 64 + lq * 16) ^ ((lr & 7) << 4);
    const int rd2 = (lr * 256 + 2 * 64 + lq * 16) ^ ((lr & 7) << 4);
    const int rd3 = (lr * 256 + 3 * 64 + lq * 16) ^ ((lr & 7) << 4);
    const int ub = (w * 16 + lr) * 2;
    const int w0 = ((lq * 4 + 0) * 256 + ub) ^ (((lq * 4 + 0) & 7) << 4);
    const int w1 = ((lq * 4 + 1) * 256 + ub) ^ (((lq * 4 + 1) & 7) << 4);
    const int w2 = ((lq * 4 + 2) * 256 + ub) ^ (((lq * 4 + 2) & 7) << 4);
    const int w3 = ((lq * 4 + 3) * 256 + ub) ^ (((lq * 4 + 3) & 7) << 4);

    int t0 = dir ? (SEQT - 1) : 0;
    const long long pstep = (dir ? -1LL : 1LL) * (4 * 512 * 16);
    const unsigned short* pptr = P2 + ((size_t)(t0 * 4 + dir * 2 + bt) * 512 + tid) * 16;
    bf16x8 pc0 = *(const bf16x8*)pptr;
    bf16x8 pc1 = *(const bf16x8*)(pptr + 8);
    pptr += pstep;

    unsigned short* hbase = H + (size_t)(bt * 16 + lq * 4) * 256 + dir * 128 + w * 16 + lr
                              + (size_t)t0 * 32 * 256;
    const long long hstep = (dir ? -1LL : 1LL) * (32 * 256);

// LDS-only barrier: order the h-tile exchange without draining vmcnt, so the
// P-prefetch (and the scattered H global stores) stay in flight across steps.
#define LBAR() asm volatile("s_waitcnt lgkmcnt(0)\n\ts_barrier" ::: "memory")

#define STEP(CUR, PF) do { \
    bf16x8 af0 = *(const bf16x8*)(hb + (CUR) * 4096 + rd0); \
    bf16x8 af1 = *(const bf16x8*)(hb + (CUR) * 4096 + rd1); \
    bf16x8 af2 = *(const bf16x8*)(hb + (CUR) * 4096 + rd2); \
    bf16x8 af3 = *(const bf16x8*)(hb + (CUR) * 4096 + rd3); \
    u32x4 u0 = __builtin_bit_cast(u32x4, pc0); \
    u32x4 u1 = __builtin_bit_cast(u32x4, pc1); \
    if (PF) { pc0 = *(const bf16x8*)pptr; pc1 = *(const bf16x8*)(pptr + 8); pptr += pstep; } \
    f32x4 a0 = {BLO(u0.x), BHI(u0.x), BLO(u0.y), BHI(u0.y)}; \
    f32x4 a1 = {BLO(u0.z), BHI(u0.z), BLO(u0.w), BHI(u0.w)}; \
    f32x4 a2 = {BLO(u1.x), BHI(u1.x), BLO(u1.y), BHI(u1.y)}; \
    f32x4 a3 = {BLO(u1.z), BHI(u1.z), BLO(u1.w), BHI(u1.w)}; \
    a0 = __builtin_amdgcn_mfma_f32_16x16x32_bf16(af0, bfrag[0][0], a0, 0, 0, 0); \
    a0 = __builtin_amdgcn_mfma_f32_16x16x32_bf16(af1, bfrag[0][1], a0, 0, 0, 0); \
    a0 = __builtin_amdgcn_mfma_f32_16x16x32_bf16(af2, bfrag[0][2], a0, 0, 0, 0); \
    a0 = __builtin_amdgcn_mfma_f32_16x16x32_bf16(af3, bfrag[0][3], a0, 0, 0, 0); \
    a1 = __builtin_amdgcn_mfma_f32_16x16x32_bf16(af0, bfrag[1][0], a1, 0, 0, 0); \
    a1 = __builtin_amdgcn_mfma_f32_16x16x32_bf16(af1, bfrag[1][1], a1, 0, 0, 0); \
    a1 = __builtin_amdgcn_mfma_f32_16x16x32_bf16(af2, bfrag[1][2], a1, 0, 0, 0); \
    a1 = __builtin_amdgcn_mfma_f32_16x16x32_bf16(af3, bfrag[1][3], a1, 0, 0, 0); \
    a2 = __builtin_amdgcn_mfma_f32_16x16x32_bf16(af0, bfrag[2][0], a2, 0, 0, 0); \
    a2 = __builtin_amdgcn_mfma_f32_16x16x32_bf16(af1, bfrag[2][1], a2, 0, 0, 0); \
    a2 = __builtin_amdgcn_mfma_f32_16x16x32_bf16(af2, bfrag[2][2], a2, 0, 0, 0); \
    a2 = __builtin_amdgcn_mfma_f32_16x16x32_bf16(af3, bfrag[2][3], a2, 0, 0, 0); \
    a3 = __builtin_amdgcn_mfma_f32_16x16x32_bf16(af0, bfrag[3][0], a3, 0, 0, 0); \
    a3 = __builtin_amdgcn_mfma_f32_16x16x32_bf16(af1, bfrag[3][1], a3, 0, 0, 0); \
    a3 = __builtin_amdgcn_mfma_f32_16x16x32_bf16(af2, bfrag[3][2], a3, 0, 0, 0); \
    a3 = __builtin_amdgcn_mfma_f32_16x16x32_bf16(af3, bfrag[3][3], a3, 0, 0, 0); \
    float hn0 = cell(a0[0], a1[0], a2[0], a3[0], c_reg[0]); \
    float hn1 = cell(a0[1], a1[1], a2[1], a3[1], c_reg[1]); \
    float hn2 = cell(a0[2], a1[2], a2[2], a3[2], c_reg[2]); \
    float hn3 = cell(a0[3], a1[3], a2[3], a3[3], c_reg[3]); \
    unsigned pk01, pk23; \
    asm("v_cvt_pk_bf16_f32 %0, %1, %2" : "=v"(pk01) : "v"(hn0), "v"(hn1)); \
    asm("v_cvt_pk_bf16_f32 %0, %1, %2" : "=v"(pk23) : "v"(hn2), "v"(hn3)); \
    unsigned short s0 = (unsigned short)pk01, s1 = (unsigned short)(pk01 >> 16); \
    unsigned short s2 = (unsigned short)pk23, s3 = (unsigned short)(pk23 >> 16); \
    char* wb = hb + (((CUR) ^ 1) * 4096); \
    *(unsigned short*)(wb + w0) = s0; \
    *(unsigned short*)(wb + w1) = s1; \
    *(unsigned short*)(wb + w2) = s2; \
    *(unsigned short*)(wb + w3) = s3; \
    hbase[0] = s0; hbase[256] = s1; hbase[512] = s2; hbase[768] = s3; \
    hbase += hstep; \
    LBAR(); \
} while (0)

    for (int it = 0; it < 1023; ++it) {
        STEP(0, true);
        STEP(1, true);
    }
    STEP(0, true);
    STEP(1, false);
#undef STEP
#undef LBAR
}

// ---------------- feats: F(65536x16) = H @ outW^T + out_b ----------------
__global__ __launch_bounds__(256) void k_feats(
    const unsigned short* __restrict__ H, const unsigned short* __restrict__ outW_bf,
    const float* __restrict__ out_b, float* __restrict__ feats)
{
    int m0 = blockIdx.x * 64;
    int tid = threadIdx.x;
    int w = tid >> 6, l = tid & 63;
    int lr = l & 15, lq = l >> 4;
    __shared__ __align__(16) unsigned short Hl[64 * 256];

    {
        int r = tid >> 2, cb = (tid & 3) * 8;
        #pragma unroll
        for (int cc = 0; cc < 8; ++cc) {
            int c = cb + cc;
            bf16x8 v = *(const bf16x8*)(H + (size_t)(m0 + r) * 256 + c * 8);
            *(bf16x8*)((char*)Hl + r * 512 + ((c * 16) ^ ((r & 7) << 4))) = v;
        }
    }
    bf16x8 bw[8];
    #pragma unroll
    for (int ko = 0; ko < 8; ++ko)
        bw[ko] = *(const bf16x8*)(outW_bf + lr * 256 + ko * 32 + lq * 8);
    __syncthreads();
    int row = w * 16 + lr;
    f32x4 acc = {0.f, 0.f, 0.f, 0.f};
    #pragma unroll
    for (int ko = 0; ko < 8; ++ko) {
        bf16x8 a = *(const bf16x8*)((char*)Hl + row * 512 + ((ko * 64 + lq * 16) ^ ((row & 7) << 4)));
        acc = __builtin_amdgcn_mfma_f32_16x16x32_bf16(a, bw[ko], acc, 0, 0, 0);
    }
    float ob = out_b[lr];
    #pragma unroll
    for (int j = 0; j < 4; ++j) {
        int m = m0 + w * 16 + lq * 4 + j;
        feats[(size_t)m * 16 + lr] = acc[j] + ob;
    }
}

// ---------------- Viterbi: 1 block per batch, 1 wave; DPP reduce + packed backtrack ----------------
template <int CTRL>
__device__ __forceinline__ float dppf(float x) {
    return __int_as_float(__builtin_amdgcn_update_dpp(0, __float_as_int(x), CTRL, 0xF, 0xF, true));
}
template <int CTRL>
__device__ __forceinline__ int dppi(int x) {
    return __builtin_amdgcn_update_dpp(0, x, CTRL, 0xF, 0xF, true);
}

__global__ __launch_bounds__(64) void k_viterbi(
    const float* __restrict__ feats, const float* __restrict__ trans,
    float* __restrict__ out)
{
    int b = blockIdx.x;
    int l = threadIdx.x;
    int i = l >> 2, s = l & 3;          // i = next-label (0..15), s = prev-quad (0..3)
    __shared__ unsigned char bp[SEQT * 16];
    __shared__ __align__(16) float fch[256 * 16];
    __shared__ unsigned long long bp64[SEQT];

    float tr[4];
    #pragma unroll
    for (int m = 0; m < 4; ++m) tr[m] = trans[i * 16 + s * 4 + m];
    float fvloc[4];
    #pragma unroll
    for (int m = 0; m < 4; ++m) fvloc[m] = (s * 4 + m == 0) ? 0.f : -10000.f;

    int ga[4];
    #pragma unroll
    for (int m = 0; m < 4; ++m) ga[m] = (16 * s + 4 * m) * 4;   // bpermute byte addr

    for (int t = 0; t < SEQT; ++t) {
        if ((t & 255) == 0) {
            __syncthreads();
            for (int k = l; k < 256; k += 64) {
                const float4* src = (const float4*)(feats + (size_t)((t + k) * 32 + b) * 16);
                float4 v0 = src[0], v1 = src[1], v2 = src[2], v3 = src[3];
                float4* dst = (float4*)(fch + k * 16);
                dst[0] = v0; dst[1] = v1; dst[2] = v2; dst[3] = v3;
            }
            __syncthreads();
        }
        float best = fvloc[0] + tr[0];
        int bj = s * 4;
        #pragma unroll
        for (int m = 1; m < 4; ++m) {
            float v = fvloc[m] + tr[m];
            if (v > best) { best = v; bj = s * 4 + m; }
        }
        { // quad xor1 via DPP quad_perm [1,0,3,2]
            float ov = dppf<0xB1>(best); int oj = dppi<0xB1>(bj);
            bool take = (ov > best) || (ov == best && oj < bj);
            best = take ? ov : best; bj = take ? oj : bj;
        }
        { // quad xor2 via DPP quad_perm [2,3,0,1]
            float ov = dppf<0x4E>(best); int oj = dppi<0x4E>(bj);
            bool take = (ov > best) || (ov == best && oj < bj);
            best = take ? ov : best; bj = take ? oj : bj;
        }
        float fvn = best + fch[(t & 255) * 16 + i];
        if (s == 0) bp[t * 16 + i] = (unsigned char)bj;
        #pragma unroll
        for (int m = 0; m < 4; ++m)
            fvloc[m] = __int_as_float(__builtin_amdgcn_ds_bpermute(ga[m], __float_as_int(fvn)));
    }
    // termination
    float bestS = fvloc[0] + trans[16 + s * 4];
    int bl = s * 4;
    #pragma unroll
    for (int m = 1; m < 4; ++m) {
        float tv = fvloc[m] + trans[16 + s * 4 + m];
        if (tv > bestS) { bestS = tv; bl = s * 4 + m; }
    }
    {
        float ov = dppf<0xB1>(bestS); int oj = dppi<0xB1>(bl);
        bool take = (ov > bestS) || (ov == bestS && oj < bl);
        bestS = take ? ov : bestS; bl = take ? oj : bl;
    }
    {
        float ov = dppf<0x4E>(bestS); int oj = dppi<0x4E>(bl);
        bool take = (ov > bestS) || (ov == bestS && oj < bl);
        bestS = take ? ov : bestS; bl = take ? oj : bl;
    }
    __syncthreads();
    // pack bp rows into nibble-u64 (address-independent backtrack reads)
    for (int t = l; t < SEQT; t += 64) {
        const uint4* p = (const uint4*)(bp + t * 16);
        uint4 u = *p;
        unsigned n0 = (u.x | (u.x >> 4)) & 0x00FF00FFu; n0 = (n0 | (n0 >> 8)) & 0xFFFFu;
        unsigned n1 = (u.y | (u.y >> 4)) & 0x00FF00FFu; n1 = (n1 | (n1 >> 8)) & 0xFFFFu;
        unsigned n2 = (u.z | (u.z >> 4)) & 0x00FF00FFu; n2 = (n2 | (n2 >> 8)) & 0xFFFFu;
        unsigned n3 = (u.w | (u.w >> 4)) & 0x00FF00FFu; n3 = (n3 | (n3 >> 8)) & 0xFFFFu;
        bp64[t] = (unsigned long long)n0 | ((unsigned long long)n1 << 16)
                | ((unsigned long long)n2 << 32) | ((unsigned long long)n3 << 48);
    }
    __syncthreads();
    if (l == 0) out[b] = bestS;
    // all lanes run the chain redundantly; lane t&63 stores t
    int lbl = bl;
    #pragma unroll 8
    for (int t = SEQT - 1; t >= 0; --t) {
        if ((t & 63) == l) out[32 + (size_t)t * 32 + b] = (float)lbl;
        lbl = (int)((bp64[t] >> (lbl * 4)) & 15ull);
    }
}

extern "C" void kernel_launch(void* const* d_in, const int* in_sizes, int n_in,
                              void* d_out, int out_size, void* d_ws, size_t ws_size,
                              hipStream_t stream) {
    const float* source = (const float*)d_in[0];
    const float* in_W  = (const float*)d_in[1];
    const float* in_b  = (const float*)d_in[2];
    const float* Wih_f = (const float*)d_in[3];
    const float* Whh_f = (const float*)d_in[4];
    const float* b_f   = (const float*)d_in[5];
    const float* Wih_b = (const float*)d_in[6];
    const float* Whh_b = (const float*)d_in[7];
    const float* b_b   = (const float*)d_in[8];
    const float* out_W = (const float*)d_in[9];
    const float* out_b = (const float*)d_in[10];
    const float* trans = (const float*)d_in[11];
    const float* h0    = (const float*)d_in[12];
    const float* c0    = (const float*)d_in[13];
    float* out = (float*)d_out;

    char* ws = (char*)d_ws;
    unsigned short* P2      = (unsigned short*)(ws);                 // 65536*1024*2 = 134217728
    unsigned short* H       = (unsigned short*)(ws + 134217728);     // 65536*256*2  =  33554432
    float*          feats   = (float*)         (ws + 167772160);     // 65536*16*4   =   4194304
    unsigned short* Wc      = (unsigned short*)(ws + 171966464);     // 1024*512*2   =   1048576
    float*          bc      = (float*)         (ws + 173015040);     // 1024*4
    unsigned short* Whh_bf  = (unsigned short*)(ws + 173019136);     // 1024*128*2   =    262144
    unsigned short* outW_bf = (unsigned short*)(ws + 173281280);     // 16*256*2
    // total ~173.3 MB

    hipLaunchKernelGGL(k_prep_wc, dim3(128), dim3(256), 0, stream,
                       in_W, in_b, Wih_f, b_f, Wih_b, b_b, Wc, bc);
    hipLaunchKernelGGL(k_prep_misc, dim3(256), dim3(256), 0, stream,
                       Whh_f, Whh_b, out_W, Whh_bf, outW_bf);
    hipLaunchKernelGGL(k_gemm_p, dim3(4, 1024), dim3(512), 0, stream,
                       source, Wc, bc, P2);
    hipLaunchKernelGGL(k_lstm, dim3(4), dim3(512), 0, stream,
                       P2, Whh_bf, h0, c0, H);
    hipLaunchKernelGGL(k_feats, dim3(1024), dim3(256), 0, stream,
                       H, outW_bf, out_b, feats);
    hipLaunchKernelGGL(k_viterbi, dim3(32), dim3(64), 0, stream,
                       feats, trans, out);
}

// Round 7
// 2320.116 us; speedup vs baseline: 1.4346x; 1.0075x over previous
//
#include <hip/hip_runtime.h>
#include <hip/hip_bf16.h>

typedef __attribute__((ext_vector_type(8))) short bf16x8;
typedef __attribute__((ext_vector_type(4))) float f32x4;
typedef __attribute__((ext_vector_type(4))) unsigned u32x4;
typedef __attribute__((ext_vector_type(2))) unsigned u32x2;

#define SEQT 2048
#define BATCH 32
#define INDIM 512
#define EMB 256
#define HHX 128
#define LBL 16
#define LOG2E 1.44269504f

__device__ __forceinline__ unsigned short f2bf(float f) {
    unsigned u = __float_as_uint(f);
    u += 0x7FFFu + ((u >> 16) & 1u);
    return (unsigned short)(u >> 16);
}
#define BLO(u) __uint_as_float((u) << 16)
#define BHI(u) __uint_as_float((u) & 0xffff0000u)

// Fused-denominator cell: 5 exp2 + 2 rcp. Inputs pre-scaled (-LOG2E for i,f,o;
// +2*LOG2E for g). All positive exp2 args clamped so no factor product overflows
// (max ~2^120 < inf) -> NaN-proof saturation.
__device__ __forceinline__ float cell(float ig, float fg, float gg, float og, float& c) {
    float Ef = __builtin_amdgcn_exp2f(fminf(fg, 30.f));
    float Ei = __builtin_amdgcn_exp2f(fminf(ig, 30.f));
    float Eg = __builtin_amdgcn_exp2f(fminf(gg, 60.f));
    float Eo = __builtin_amdgcn_exp2f(fminf(og, 30.f));
    float pf = 1.f + Ef;
    float t1 = (Eg + 1.f) * (1.f + Ei);
    float num = c * t1 + (Eg - 1.f) * pf;
    float cn = num * __builtin_amdgcn_rcpf(pf * t1);
    c = cn;
    float E2 = __builtin_amdgcn_exp2f(fminf(2.f * LOG2E * cn, 60.f));
    float r3 = __builtin_amdgcn_rcpf((E2 + 1.f) * (1.f + Eo));
    return (E2 - 1.f) * r3;
}

// Gate-row permutation: g' = w*64 + q*16 + r  <->  orig = q*128 + w*16 + r
// q = gate (0=i,1=f,2=g,3=o)
__device__ __forceinline__ int orig_of(int gp) {
    return ((gp >> 4) & 3) * 128 + (gp >> 6) * 16 + (gp & 15);
}
__device__ __forceinline__ float gate_scale(int gp) {
    return (((gp >> 4) & 3) == 2) ? (2.f * LOG2E) : (-LOG2E);
}

// ---------------- prep: combined W (Wih @ in_W) + bias, permuted+scaled rows ----------------
__global__ __launch_bounds__(256) void k_prep_wc(
    const float* __restrict__ in_W, const float* __restrict__ in_b,
    const float* __restrict__ Wih_f, const float* __restrict__ b_f,
    const float* __restrict__ Wih_b, const float* __restrict__ b_b,
    unsigned short* __restrict__ Wc, float* __restrict__ bc)
{
    int G0 = blockIdx.x * 8;         // 128 blocks
    int tid = threadIdx.x;
    __shared__ float wrow[8][EMB];
    for (int e = tid; e < 8 * EMB; e += 256) {
        int r = e >> 8, ee = e & 255;
        int G = G0 + r, dir = G >> 9, gp = G & 511;
        wrow[r][ee] = (dir ? Wih_b : Wih_f)[orig_of(gp) * EMB + ee] * gate_scale(gp);
    }
    __syncthreads();
    for (int k = tid; k < INDIM; k += 256) {
        float acc[8] = {0, 0, 0, 0, 0, 0, 0, 0};
        #pragma unroll 4
        for (int e = 0; e < EMB; ++e) {
            float x = in_W[e * INDIM + k];
            #pragma unroll
            for (int r = 0; r < 8; ++r) acc[r] += wrow[r][e] * x;
        }
        #pragma unroll
        for (int r = 0; r < 8; ++r) Wc[(size_t)(G0 + r) * INDIM + k] = f2bf(acc[r]);
    }
    if (tid < 64) {
        for (int r = 0; r < 8; ++r) {
            float p = 0.f;
            for (int e = tid; e < EMB; e += 64) p += wrow[r][e] * in_b[e];
            for (int off = 32; off; off >>= 1) p += __shfl_xor(p, off);
            if (tid == 0) {
                int G = G0 + r, dir = G >> 9, gp = G & 511;
                bc[G] = (dir ? b_b : b_f)[orig_of(gp)] * gate_scale(gp) + p;
            }
        }
    }
}

// ---------------- prep: bf16 converts (Whh permuted+scaled, out_W) ----------------
__global__ __launch_bounds__(256) void k_prep_misc(
    const float* __restrict__ Whh_f, const float* __restrict__ Whh_b,
    const float* __restrict__ out_W,
    unsigned short* __restrict__ Whh_bf, unsigned short* __restrict__ outW_bf)
{
    int idx = blockIdx.x * 256 + threadIdx.x;
    int stride = gridDim.x * 256;
    for (int i = idx; i < 1024 * HHX; i += stride) {
        int G = i >> 7, k = i & 127;
        int dir = G >> 9, gp = G & 511;
        const float* Whh = dir ? Whh_b : Whh_f;
        Whh_bf[i] = f2bf(Whh[orig_of(gp) * HHX + k] * gate_scale(gp));
    }
    for (int i = idx; i < LBL * 256; i += stride) outW_bf[i] = f2bf(out_W[i]);
}

// ---------------- big GEMM: P2 = S @ Wc^T + bc ----------------
// P2[(t*16 + dir*8 + bt4)][owner=unit(128)][16 = q*4 + j(batch within 4-tile)]
__global__ __launch_bounds__(512) void k_gemm_p(
    const float* __restrict__ S, const unsigned short* __restrict__ Wc,
    const float* __restrict__ bc, unsigned short* __restrict__ P2)
{
    int m0 = blockIdx.y * 64;
    int n0 = blockIdx.x * 256;
    int tid = threadIdx.x;
    int w = tid >> 6, l = tid & 63;
    int lr = l & 15, lq = l >> 4;
    int wm = w >> 2, wn = w & 3;

    __shared__ __align__(16) unsigned short Alds[64 * 64];
    __shared__ __align__(16) unsigned short Blds[256 * 64];

    const f32x4 fzero = {0.f, 0.f, 0.f, 0.f};
    f32x4 acc[2][4];
    #pragma unroll
    for (int a = 0; a < 2; ++a)
        #pragma unroll
        for (int b = 0; b < 4; ++b) acc[a][b] = fzero;

    for (int kt = 0; kt < 8; ++kt) {
        { // stage A (convert fp32->bf16 via cvt_pk, XOR-swizzled rows of 128B)
            int r = tid >> 3, c = tid & 7;
            const float* src = S + (size_t)(m0 + r) * INDIM + kt * 64 + c * 8;
            float4 v0 = *(const float4*)src;
            float4 v1 = *(const float4*)(src + 4);
            unsigned g0, g1, g2, g3;
            asm("v_cvt_pk_bf16_f32 %0, %1, %2" : "=v"(g0) : "v"(v0.x), "v"(v0.y));
            asm("v_cvt_pk_bf16_f32 %0, %1, %2" : "=v"(g1) : "v"(v0.z), "v"(v0.w));
            asm("v_cvt_pk_bf16_f32 %0, %1, %2" : "=v"(g2) : "v"(v1.x), "v"(v1.y));
            asm("v_cvt_pk_bf16_f32 %0, %1, %2" : "=v"(g3) : "v"(v1.z), "v"(v1.w));
            u32x4 wv = {g0, g1, g2, g3};
            *(u32x4*)((char*)Alds + r * 128 + ((c * 16) ^ ((r & 7) << 4))) = wv;
        }
        { // stage B
            int r = tid >> 1, h = tid & 1;
            const unsigned short* bs = Wc + (size_t)(n0 + r) * INDIM + kt * 64;
            #pragma unroll
            for (int cc = 0; cc < 4; ++cc) {
                int ch = h * 4 + cc;
                bf16x8 v = *(const bf16x8*)(bs + ch * 8);
                *(bf16x8*)((char*)Blds + r * 128 + ((ch * 16) ^ ((r & 7) << 4))) = v;
            }
        }
        __syncthreads();
        bf16x8 af[2][2], bfv[4][2];
        #pragma unroll
        for (int tm = 0; tm < 2; ++tm)
            #pragma unroll
            for (int kk = 0; kk < 2; ++kk) {
                int ra = wm * 32 + tm * 16 + lr;
                af[tm][kk] = *(const bf16x8*)((char*)Alds + ra * 128 + ((kk * 64 + lq * 16) ^ ((ra & 7) << 4)));
            }
        #pragma unroll
        for (int tn = 0; tn < 4; ++tn)
            #pragma unroll
            for (int kk = 0; kk < 2; ++kk) {
                int rb = wn * 64 + tn * 16 + lr;
                bfv[tn][kk] = *(const bf16x8*)((char*)Blds + rb * 128 + ((kk * 64 + lq * 16) ^ ((rb & 7) << 4)));
            }
        #pragma unroll
        for (int tm = 0; tm < 2; ++tm)
            #pragma unroll
            for (int tn = 0; tn < 4; ++tn)
                #pragma unroll
                for (int kk = 0; kk < 2; ++kk)
                    acc[tm][tn] = __builtin_amdgcn_mfma_f32_16x16x32_bf16(af[tm][kk], bfv[tn][kk], acc[tm][tn], 0, 0, 0);
        __syncthreads();
    }
    // epilogue: 4 batch-j values of one gate -> one u32x2 store into new P2 layout
    #pragma unroll
    for (int tn = 0; tn < 4; ++tn) {
        int n = n0 + wn * 64 + tn * 16 + lr;
        float bias = bc[n];
        int dir2 = n >> 9, nn = n & 511;
        int w2 = nn >> 6, q2 = (nn >> 4) & 3, lr2 = nn & 15;
        #pragma unroll
        for (int tm = 0; tm < 2; ++tm) {
            int m0j = m0 + wm * 32 + tm * 16 + lq * 4;
            int t = m0j >> 5, mb = m0j & 31;
            int bt2 = mb >> 2;
            size_t base = ((size_t)(t * 16 + dir2 * 8 + bt2) * 128 + w2 * 16 + lr2) * 16 + q2 * 4;
            float f0 = acc[tm][tn][0] + bias, f1 = acc[tm][tn][1] + bias;
            float f2 = acc[tm][tn][2] + bias, f3 = acc[tm][tn][3] + bias;
            unsigned p01, p23;
            asm("v_cvt_pk_bf16_f32 %0, %1, %2" : "=v"(p01) : "v"(f0), "v"(f1));
            asm("v_cvt_pk_bf16_f32 %0, %1, %2" : "=v"(p23) : "v"(f2), "v"(f3));
            *(u32x2*)(P2 + base) = (u32x2){p01, p23};
        }
    }
}

// ---------------- LSTM recurrence: 16 blocks (dir x 8 batch-tiles of 4), 512 threads ----------------
// Each block: 4 batch rows x 128 units = 512 cells -> exactly 1 cell/thread after
// a ds_bpermute redistribution of the MFMA outputs (valid rows live in lanes 0-15).
__global__ __launch_bounds__(512) void k_lstm(
    const unsigned short* __restrict__ P2, const unsigned short* __restrict__ Whh_bf,
    const float* __restrict__ h0, const float* __restrict__ c0,
    unsigned short* __restrict__ H)
{
    int blk = blockIdx.x;
    int dir = blk >> 3, bt = blk & 7;
    int tid = threadIdx.x;
    int w = tid >> 6, l = tid & 63;
    int lr = l & 15, lq = l >> 4;

    __shared__ __align__(16) unsigned short hbuf[2][16 * 128];
    char* hb = (char*)hbuf;

    // Whh fragments: wave w owns gates q=0..3 of units [w*16, w*16+16)
    bf16x8 bfrag[4][4];
    #pragma unroll
    for (int q = 0; q < 4; ++q)
        #pragma unroll
        for (int ko = 0; ko < 4; ++ko) {
            int row = dir * 512 + w * 64 + q * 16 + lr;
            bfrag[q][ko] = *(const bf16x8*)(Whh_bf + (size_t)row * HHX + ko * 32 + lq * 8);
        }

    // this thread's cell: batch = lq (0..3), unit = w*16+lr
    float c_reg = c0[(dir * 32 + bt * 4 + lq) * HHX + w * 16 + lr];

    // stage h0 into buf0 rows 0-3, zero rows 4-15; buf1 all zero (rows 0-3 rewritten at step 0)
    for (int e = tid; e < 2048; e += 512) {
        int b = e >> 7, u = e & 127;
        unsigned short v = 0;
        if (b < 4) v = f2bf(h0[(dir * 32 + bt * 4 + b) * HHX + u]);
        int addr = (b * 256 + u * 2) ^ ((b & 7) << 4);
        *(unsigned short*)(hb + addr) = v;
        *(unsigned short*)(hb + 4096 + addr) = 0;
    }
    __syncthreads();

    // loop-invariant LDS offsets
    const int rd0 = (lr * 256 + 0 * 64 + lq * 16) ^ ((lr & 7) << 4);
    const int rd1 = (lr * 256 + 1 * 64 + lq * 16) ^ ((lr & 7) << 4);
    const int rd2 = (lr * 256 + 2 * 64 + lq * 16) ^ ((lr & 7) << 4);
    const int rd3 = (lr * 256 + 3 * 64 + lq * 16) ^ ((lr & 7) << 4);
    const int wa = (lq * 256 + (w * 16 + lr) * 2) ^ (lq << 4);
    const int ba = lr << 2;   // bpermute source byte addr (lane l&15)

    int t0 = dir ? (SEQT - 1) : 0;
    const long long pstep = (dir ? -1LL : 1LL) * (16LL * 128 * 16);
    const unsigned short* pptr = P2 + ((size_t)(t0 * 16 + dir * 8 + bt) * 128 + w * 16 + lr) * 16;
    bf16x8 pc0 = *(const bf16x8*)pptr;
    bf16x8 pc1 = *(const bf16x8*)(pptr + 8);
    pptr += pstep;

    unsigned short* hptr = H + (size_t)(t0 * 32 + bt * 4 + lq) * 256 + dir * 128 + w * 16 + lr;
    const long long hstep = (dir ? -1LL : 1LL) * (32 * 256);

#define BPERM(x) __int_as_float(__builtin_amdgcn_ds_bpermute(ba, __float_as_int(x)))
// LDS-only barrier: don't drain vmcnt (keep P prefetch + H stores in flight)
#define LBAR() asm volatile("s_waitcnt lgkmcnt(0)\n\ts_barrier" ::: "memory")

#define STEP(CUR, PF) do { \
    bf16x8 af0 = *(const bf16x8*)(hb + (CUR) * 4096 + rd0); \
    bf16x8 af1 = *(const bf16x8*)(hb + (CUR) * 4096 + rd1); \
    bf16x8 af2 = *(const bf16x8*)(hb + (CUR) * 4096 + rd2); \
    bf16x8 af3 = *(const bf16x8*)(hb + (CUR) * 4096 + rd3); \
    u32x4 u0 = __builtin_bit_cast(u32x4, pc0); \
    u32x4 u1 = __builtin_bit_cast(u32x4, pc1); \
    if (PF) { pc0 = *(const bf16x8*)pptr; pc1 = *(const bf16x8*)(pptr + 8); pptr += pstep; } \
    f32x4 a0 = {BLO(u0.x), BHI(u0.x), BLO(u0.y), BHI(u0.y)}; \
    f32x4 a1 = {BLO(u0.z), BHI(u0.z), BLO(u0.w), BHI(u0.w)}; \
    f32x4 a2 = {BLO(u1.x), BHI(u1.x), BLO(u1.y), BHI(u1.y)}; \
    f32x4 a3 = {BLO(u1.z), BHI(u1.z), BLO(u1.w), BHI(u1.w)}; \
    a0 = __builtin_amdgcn_mfma_f32_16x16x32_bf16(af0, bfrag[0][0], a0, 0, 0, 0); \
    a0 = __builtin_amdgcn_mfma_f32_16x16x32_bf16(af1, bfrag[0][1], a0, 0, 0, 0); \
    a0 = __builtin_amdgcn_mfma_f32_16x16x32_bf16(af2, bfrag[0][2], a0, 0, 0, 0); \
    a0 = __builtin_amdgcn_mfma_f32_16x16x32_bf16(af3, bfrag[0][3], a0, 0, 0, 0); \
    a1 = __builtin_amdgcn_mfma_f32_16x16x32_bf16(af0, bfrag[1][0], a1, 0, 0, 0); \
    a1 = __builtin_amdgcn_mfma_f32_16x16x32_bf16(af1, bfrag[1][1], a1, 0, 0, 0); \
    a1 = __builtin_amdgcn_mfma_f32_16x16x32_bf16(af2, bfrag[1][2], a1, 0, 0, 0); \
    a1 = __builtin_amdgcn_mfma_f32_16x16x32_bf16(af3, bfrag[1][3], a1, 0, 0, 0); \
    a2 = __builtin_amdgcn_mfma_f32_16x16x32_bf16(af0, bfrag[2][0], a2, 0, 0, 0); \
    a2 = __builtin_amdgcn_mfma_f32_16x16x32_bf16(af1, bfrag[2][1], a2, 0, 0, 0); \
    a2 = __builtin_amdgcn_mfma_f32_16x16x32_bf16(af2, bfrag[2][2], a2, 0, 0, 0); \
    a2 = __builtin_amdgcn_mfma_f32_16x16x32_bf16(af3, bfrag[2][3], a2, 0, 0, 0); \
    a3 = __builtin_amdgcn_mfma_f32_16x16x32_bf16(af0, bfrag[3][0], a3, 0, 0, 0); \
    a3 = __builtin_amdgcn_mfma_f32_16x16x32_bf16(af1, bfrag[3][1], a3, 0, 0, 0); \
    a3 = __builtin_amdgcn_mfma_f32_16x16x32_bf16(af2, bfrag[3][2], a3, 0, 0, 0); \
    a3 = __builtin_amdgcn_mfma_f32_16x16x32_bf16(af3, bfrag[3][3], a3, 0, 0, 0); \
    /* redistribute: lane l takes gate values for (batch=lq, unit=w*16+lr) from lane lr */ \
    float g0, g1, g2, g3; \
    { \
        float v1, v2, v3, glo, ghi; \
        v1 = BPERM(a0[1]); v2 = BPERM(a0[2]); v3 = BPERM(a0[3]); \
        glo = (lq == 0) ? a0[0] : v1; ghi = (lq == 2) ? v2 : v3; g0 = (lq < 2) ? glo : ghi; \
        v1 = BPERM(a1[1]); v2 = BPERM(a1[2]); v3 = BPERM(a1[3]); \
        glo = (lq == 0) ? a1[0] : v1; ghi = (lq == 2) ? v2 : v3; g1 = (lq < 2) ? glo : ghi; \
        v1 = BPERM(a2[1]); v2 = BPERM(a2[2]); v3 = BPERM(a2[3]); \
        glo = (lq == 0) ? a2[0] : v1; ghi = (lq == 2) ? v2 : v3; g2 = (lq < 2) ? glo : ghi; \
        v1 = BPERM(a3[1]); v2 = BPERM(a3[2]); v3 = BPERM(a3[3]); \
        glo = (lq == 0) ? a3[0] : v1; ghi = (lq == 2) ? v2 : v3; g3 = (lq < 2) ? glo : ghi; \
    } \
    float hn = cell(g0, g1, g2, g3, c_reg); \
    unsigned pk; \
    asm("v_cvt_pk_bf16_f32 %0, %1, %2" : "=v"(pk) : "v"(hn), "v"(hn)); \
    unsigned short s = (unsigned short)pk; \
    *(unsigned short*)(hb + (((CUR) ^ 1) * 4096) + wa) = s; \
    hptr[0] = s; \
    hptr += hstep; \
    LBAR(); \
} while (0)

    for (int it = 0; it < 1023; ++it) {
        STEP(0, true);
        STEP(1, true);
    }
    STEP(0, true);
    STEP(1, false);
#undef STEP
#undef LBAR
#undef BPERM
}

// ---------------- feats: F(65536x16) = H @ outW^T + out_b ----------------
__global__ __launch_bounds__(256) void k_feats(
    const unsigned short* __restrict__ H, const unsigned short* __restrict__ outW_bf,
    const float* __restrict__ out_b, float* __restrict__ feats)
{
    int m0 = blockIdx.x * 64;
    int tid = threadIdx.x;
    int w = tid >> 6, l = tid & 63;
    int lr = l & 15, lq = l >> 4;
    __shared__ __align__(16) unsigned short Hl[64 * 256];

    {
        int r = tid >> 2, cb = (tid & 3) * 8;
        #pragma unroll
        for (int cc = 0; cc < 8; ++cc) {
            int c = cb + cc;
            bf16x8 v = *(const bf16x8*)(H + (size_t)(m0 + r) * 256 + c * 8);
            *(bf16x8*)((char*)Hl + r * 512 + ((c * 16) ^ ((r & 7) << 4))) = v;
        }
    }
    bf16x8 bw[8];
    #pragma unroll
    for (int ko = 0; ko < 8; ++ko)
        bw[ko] = *(const bf16x8*)(outW_bf + lr * 256 + ko * 32 + lq * 8);
    __syncthreads();
    int row = w * 16 + lr;
    f32x4 acc = {0.f, 0.f, 0.f, 0.f};
    #pragma unroll
    for (int ko = 0; ko < 8; ++ko) {
        bf16x8 a = *(const bf16x8*)((char*)Hl + row * 512 + ((ko * 64 + lq * 16) ^ ((row & 7) << 4)));
        acc = __builtin_amdgcn_mfma_f32_16x16x32_bf16(a, bw[ko], acc, 0, 0, 0);
    }
    float ob = out_b[lr];
    #pragma unroll
    for (int j = 0; j < 4; ++j) {
        int m = m0 + w * 16 + lq * 4 + j;
        feats[(size_t)m * 16 + lr] = acc[j] + ob;
    }
}

// ---------------- Viterbi: 1 block per batch, 1 wave; DPP reduce + packed backtrack ----------------
template <int CTRL>
__device__ __forceinline__ float dppf(float x) {
    return __int_as_float(__builtin_amdgcn_update_dpp(0, __float_as_int(x), CTRL, 0xF, 0xF, true));
}
template <int CTRL>
__device__ __forceinline__ int dppi(int x) {
    return __builtin_amdgcn_update_dpp(0, x, CTRL, 0xF, 0xF, true);
}

__global__ __launch_bounds__(64) void k_viterbi(
    const float* __restrict__ feats, const float* __restrict__ trans,
    float* __restrict__ out)
{
    int b = blockIdx.x;
    int l = threadIdx.x;
    int i = l >> 2, s = l & 3;          // i = next-label (0..15), s = prev-quad (0..3)
    __shared__ unsigned char bp[SEQT * 16];
    __shared__ __align__(16) float fch[256 * 16];
    __shared__ unsigned long long bp64[SEQT];

    float tr[4];
    #pragma unroll
    for (int m = 0; m < 4; ++m) tr[m] = trans[i * 16 + s * 4 + m];
    float fvloc[4];
    #pragma unroll
    for (int m = 0; m < 4; ++m) fvloc[m] = (s * 4 + m == 0) ? 0.f : -10000.f;

    int ga[4];
    #pragma unroll
    for (int m = 0; m < 4; ++m) ga[m] = (16 * s + 4 * m) * 4;   // bpermute byte addr

    for (int t = 0; t < SEQT; ++t) {
        if ((t & 255) == 0) {
            __syncthreads();
            for (int k = l; k < 256; k += 64) {
                const float4* src = (const float4*)(feats + (size_t)((t + k) * 32 + b) * 16);
                float4 v0 = src[0], v1 = src[1], v2 = src[2], v3 = src[3];
                float4* dst = (float4*)(fch + k * 16);
                dst[0] = v0; dst[1] = v1; dst[2] = v2; dst[3] = v3;
            }
            __syncthreads();
        }
        float best = fvloc[0] + tr[0];
        int bj = s * 4;
        #pragma unroll
        for (int m = 1; m < 4; ++m) {
            float v = fvloc[m] + tr[m];
            if (v > best) { best = v; bj = s * 4 + m; }
        }
        { // quad xor1 via DPP quad_perm [1,0,3,2]
            float ov = dppf<0xB1>(best); int oj = dppi<0xB1>(bj);
            bool take = (ov > best) || (ov == best && oj < bj);
            best = take ? ov : best; bj = take ? oj : bj;
        }
        { // quad xor2 via DPP quad_perm [2,3,0,1]
            float ov = dppf<0x4E>(best); int oj = dppi<0x4E>(bj);
            bool take = (ov > best) || (ov == best && oj < bj);
            best = take ? ov : best; bj = take ? oj : bj;
        }
        float fvn = best + fch[(t & 255) * 16 + i];
        if (s == 0) bp[t * 16 + i] = (unsigned char)bj;
        #pragma unroll
        for (int m = 0; m < 4; ++m)
            fvloc[m] = __int_as_float(__builtin_amdgcn_ds_bpermute(ga[m], __float_as_int(fvn)));
    }
    // termination
    float bestS = fvloc[0] + trans[16 + s * 4];
    int bl = s * 4;
    #pragma unroll
    for (int m = 1; m < 4; ++m) {
        float tv = fvloc[m] + trans[16 + s * 4 + m];
        if (tv > bestS) { bestS = tv; bl = s * 4 + m; }
    }
    {
        float ov = dppf<0xB1>(bestS); int oj = dppi<0xB1>(bl);
        bool take = (ov > bestS) || (ov == bestS && oj < bl);
        bestS = take ? ov : bestS; bl = take ? oj : bl;
    }
    {
        float ov = dppf<0x4E>(bestS); int oj = dppi<0x4E>(bl);
        bool take = (ov > bestS) || (ov == bestS && oj < bl);
        bestS = take ? ov : bestS; bl = take ? oj : bl;
    }
    __syncthreads();
    // pack bp rows into nibble-u64 (address-independent backtrack reads)
    for (int t = l; t < SEQT; t += 64) {
        const uint4* p = (const uint4*)(bp + t * 16);
        uint4 u = *p;
        unsigned n0 = (u.x | (u.x >> 4)) & 0x00FF00FFu; n0 = (n0 | (n0 >> 8)) & 0xFFFFu;
        unsigned n1 = (u.y | (u.y >> 4)) & 0x00FF00FFu; n1 = (n1 | (n1 >> 8)) & 0xFFFFu;
        unsigned n2 = (u.z | (u.z >> 4)) & 0x00FF00FFu; n2 = (n2 | (n2 >> 8)) & 0xFFFFu;
        unsigned n3 = (u.w | (u.w >> 4)) & 0x00FF00FFu; n3 = (n3 | (n3 >> 8)) & 0xFFFFu;
        bp64[t] = (unsigned long long)n0 | ((unsigned long long)n1 << 16)
                | ((unsigned long long)n2 << 32) | ((unsigned long long)n3 << 48);
    }
    __syncthreads();
    if (l == 0) out[b] = bestS;
    // all lanes run the chain redundantly; lane t&63 stores t
    int lbl = bl;
    #pragma unroll 8
    for (int t = SEQT - 1; t >= 0; --t) {
        if ((t & 63) == l) out[32 + (size_t)t * 32 + b] = (float)lbl;
        lbl = (int)((bp64[t] >> (lbl * 4)) & 15ull);
    }
}

extern "C" void kernel_launch(void* const* d_in, const int* in_sizes, int n_in,
                              void* d_out, int out_size, void* d_ws, size_t ws_size,
                              hipStream_t stream) {
    const float* source = (const float*)d_in[0];
    const float* in_W  = (const float*)d_in[1];
    const float* in_b  = (const float*)d_in[2];
    const float* Wih_f = (const float*)d_in[3];
    const float* Whh_f = (const float*)d_in[4];
    const float* b_f   = (const float*)d_in[5];
    const float* Wih_b = (const float*)d_in[6];
    const float* Whh_b = (const float*)d_in[7];
    const float* b_b   = (const float*)d_in[8];
    const float* out_W = (const float*)d_in[9];
    const float* out_b = (const float*)d_in[10];
    const float* trans = (const float*)d_in[11];
    const float* h0    = (const float*)d_in[12];
    const float* c0    = (const float*)d_in[13];
    float* out = (float*)d_out;

    char* ws = (char*)d_ws;
    unsigned short* P2      = (unsigned short*)(ws);                 // 2048*16*128*16*2 = 134217728
    unsigned short* H       = (unsigned short*)(ws + 134217728);     // 65536*256*2  =  33554432
    float*          feats   = (float*)         (ws + 167772160);     // 65536*16*4   =   4194304
    unsigned short* Wc      = (unsigned short*)(ws + 171966464);     // 1024*512*2   =   1048576
    float*          bc      = (float*)         (ws + 173015040);     // 1024*4
    unsigned short* Whh_bf  = (unsigned short*)(ws + 173019136);     // 1024*128*2   =    262144
    unsigned short* outW_bf = (unsigned short*)(ws + 173281280);     // 16*256*2
    // total ~173.3 MB

    hipLaunchKernelGGL(k_prep_wc, dim3(128), dim3(256), 0, stream,
                       in_W, in_b, Wih_f, b_f, Wih_b, b_b, Wc, bc);
    hipLaunchKernelGGL(k_prep_misc, dim3(256), dim3(256), 0, stream,
                       Whh_f, Whh_b, out_W, Whh_bf, outW_bf);
    hipLaunchKernelGGL(k_gemm_p, dim3(4, 1024), dim3(512), 0, stream,
                       source, Wc, bc, P2);
    hipLaunchKernelGGL(k_lstm, dim3(16), dim3(512), 0, stream,
                       P2, Whh_bf, h0, c0, H);
    hipLaunchKernelGGL(k_feats, dim3(1024), dim3(256), 0, stream,
                       H, outW_bf, out_b, feats);
    hipLaunchKernelGGL(k_viterbi, dim3(32), dim3(64), 0, stream,
                       feats, trans, out);
}